// Round 5
// baseline (1083.956 us; speedup 1.0000x reference)
//
#include <hip/hip_runtime.h>
#include <stdint.h>

// ---------------------------------------------------------------------------
// Conv-SNN, 100 steps, B=64, BETA=0.
// Round 5: round 4 with the conv1 staging bug fixed — a 256-thread block can
// span THREE (tq,b) frames (256 = 196 + up to 60 across two boundaries), so
// stage 3 frames in LDS, not 2. All else identical to round 4.
// f64 accumulation, identical summation order to round 3 (absmax 0.0).
// ---------------------------------------------------------------------------

#define NSTEPS 100
#define NB 64

__device__ __forceinline__ uint32_t rotl32(uint32_t v, uint32_t r) {
  return (v << r) | (v >> (32u - r));
}

__device__ __forceinline__ void threefry2x32(uint32_t k0, uint32_t k1,
                                             uint32_t& x0, uint32_t& x1) {
  uint32_t k2 = k0 ^ k1 ^ 0x1BD11BDAu;
  x0 += k0; x1 += k1;
#define TF_R(r) { x0 += x1; x1 = rotl32(x1, r); x1 ^= x0; }
  TF_R(13u) TF_R(15u) TF_R(26u) TF_R(6u)
  x0 += k1; x1 += k2 + 1u;
  TF_R(17u) TF_R(29u) TF_R(16u) TF_R(24u)
  x0 += k2; x1 += k0 + 2u;
  TF_R(13u) TF_R(15u) TF_R(26u) TF_R(6u)
  x0 += k0; x1 += k1 + 3u;
  TF_R(17u) TF_R(29u) TF_R(16u) TF_R(24u)
  x0 += k1; x1 += k2 + 4u;
  TF_R(13u) TF_R(15u) TF_R(26u) TF_R(6u)
  x0 += k2; x1 += k0 + 5u;
#undef TF_R
}

__device__ __forceinline__ double fold_pool_w(const float* W, int base, int pos) {
  int iy = pos / 6, ix = pos % 6;
  double w = 0.0;
  for (int dy = 0; dy < 2; ++dy) {
    int ky = iy - dy; if (ky < 0 || ky > 4) continue;
    for (int dx = 0; dx < 2; ++dx) {
      int kx = ix - dx; if (kx < 0 || kx > 4) continue;
      w += (double)W[base + ky * 5 + kx];
    }
  }
  return w;
}

// Fused folded-pool weights.
// W1R: [og4][pos36][c3][oj8]   (oc = og*8+oj)
// W2R: [og4][c32][pos36][oj16] (oc = og*16+oj)
__global__ __launch_bounds__(256) void weff_all(const float* __restrict__ W_in,
                                                const float* __restrict__ W_h1,
                                                double* __restrict__ W1R,
                                                double* __restrict__ W2R) {
  int e = blockIdx.x * 256 + threadIdx.x;
  if (e < 3456) {
    int oj = e & 7, c = (e >> 3) % 3, pos = ((e >> 3) / 3) % 36, og = (e >> 3) / 108;
    int oc = og * 8 + oj;
    W1R[e] = fold_pool_w(W_in, (oc * 3 + c) * 25, pos);
  } else if (e < 3456 + 73728) {
    int e2 = e - 3456;
    int oj = e2 & 15, pos = (e2 >> 4) % 36, c = ((e2 >> 4) / 36) % 32, og = e2 / 18432;
    int oc = og * 16 + oj;
    W2R[e2] = fold_pool_w(W_h1, (oc * 32 + c) * 25, pos);
  }
}

// --- spike gen: per-pixel 3-bit channel codes [t,b,1024] bytes ------------
__global__ __launch_bounds__(256) void gen_spikes(const float* __restrict__ x,
                                                  unsigned char* __restrict__ spk0c) {
  int g = blockIdx.x * 256 + threadIdx.x;
  if (g >= NSTEPS * NB * 1024) return;
  int tb = g >> 10, pix = g & 1023;
  int b = tb & 63;
  unsigned code = 0;
  #pragma unroll
  for (int c = 0; c < 3; ++c) {
    uint32_t i = (uint32_t)((tb * 3 + c) * 1024 + pix);
    uint32_t x0 = 0u, x1 = i;
    threefry2x32(0u, 1u, x0, x1);
    uint32_t bits = x0 ^ x1;
    float u = __uint_as_float((bits >> 9) | 0x3f800000u) - 1.0f;
    float xv = x[(b * 3 + c) * 1024 + pix];
    code |= (u < 2.0f * xv) ? (1u << c) : 0u;
  }
  spk0c[g] = (unsigned char)code;
}

// --- conv1+pool, 4 t per thread, flat over (tq,b,p), emits A/B bytes ------
// grid: (1225, 4og). Block spans at most 3 (tq,b) frames; all staged in LDS.
__global__ __launch_bounds__(256, 4) void conv1_ab(const unsigned char* __restrict__ spk0c,
                                                   const double* __restrict__ W1R,
                                                   unsigned char* __restrict__ A1,
                                                   unsigned char* __restrict__ B1) {
  const int og  = blockIdx.y;
  const int tid = threadIdx.x;
  const int id0 = blockIdx.x * 256;
  const int id  = id0 + tid;
  const int tb0 = id0 / 196;               // first (tq*64+b) in block
  __shared__ unsigned char sC[3][4][1024]; // [seg][tt][pix]

  #pragma unroll
  for (int k = 0; k < 3; ++k) {
    int idx = tid + k * 256;               // 0..767
    int fi = idx >> 6, lane = idx & 63;    // fi 0..11
    int seg = fi >> 2, tt = fi & 3;        // seg 0..2
    int tb = tb0 + seg; if (tb > 1599) tb = 1599;
    int b = tb & 63, tq = tb >> 6;
    ((uint4*)sC)[idx] =
        ((const uint4*)(spk0c + (size_t)((tq * 4 + tt) * NB + b) * 1024))[lane];
  }
  __syncthreads();

  const int tb  = id / 196;
  const int p   = id - tb * 196;
  const int seg = tb - tb0;                // 0..2
  const int b = tb & 63, tq = tb >> 6;
  const int oh = p / 14, ow = p - oh * 14;
  const unsigned char* base = &sC[seg][0][(2 * oh) * 32 + 2 * ow];
  const double* Wb = W1R + og * 864;

  double a[32];
  #pragma unroll
  for (int i = 0; i < 32; ++i) a[i] = 0.0;

  #pragma unroll
  for (int iy = 0; iy < 6; ++iy) {
    #pragma unroll
    for (int ix = 0; ix < 6; ++ix) {
      const int pos = iy * 6 + ix, off = iy * 32 + ix;
      unsigned c0 = base[0 * 1024 + off];
      unsigned c1 = base[1 * 1024 + off];
      unsigned c2 = base[2 * 1024 + off];
      unsigned c3 = base[3 * 1024 + off];
      #pragma unroll
      for (int c = 0; c < 3; ++c) {
        double b0 = (double)((c0 >> c) & 1u);
        double b1 = (double)((c1 >> c) & 1u);
        double b2 = (double)((c2 >> c) & 1u);
        double b3 = (double)((c3 >> c) & 1u);
        const double* wp = Wb + pos * 24 + c * 8;
        #pragma unroll
        for (int oj = 0; oj < 8; ++oj) {
          double w = wp[oj];
          a[0 * 8 + oj] = fma(b0, w, a[0 * 8 + oj]);
          a[1 * 8 + oj] = fma(b1, w, a[1 * 8 + oj]);
          a[2 * 8 + oj] = fma(b2, w, a[2 * 8 + oj]);
          a[3 * 8 + oj] = fma(b3, w, a[3 * 8 + oj]);
        }
      }
    }
  }

  #pragma unroll
  for (int tt = 0; tt < 4; ++tt) {
    unsigned ab = 0, bb = 0;
    #pragma unroll
    for (int oj = 0; oj < 8; ++oj) {
      float cur = (float)(a[tt * 8 + oj] * 0.25);
      if (cur > 1.0f) ab |= 1u << oj;
      if (cur > 2.0f) bb |= 1u << oj;
    }
    int t = tq * 4 + tt;
    size_t idx = ((size_t)(t * NB + b) * 196 + p) * 4 + og;
    A1[idx] = (unsigned char)ab;
    B1[idx] = (unsigned char)bb;
  }
}

// --- LIF1 scan + fused channel-presence (atomicOr) ------------------------
__global__ __launch_bounds__(256) void scan1(const uint32_t* __restrict__ A1w,
                                             const uint32_t* __restrict__ B1w,
                                             uint32_t* __restrict__ mask1,
                                             uint32_t* __restrict__ chanAny) {
  int chain = blockIdx.x * 256 + threadIdx.x;
  if (chain >= NB * 196) return;
  int b = chain / 196, p = chain % 196;
  uint32_t prev = 0;
  #pragma unroll 4
  for (int t = 0; t < NSTEPS; ++t) {
    size_t idx = (size_t)(t * NB + b) * 196 + p;
    uint32_t A = A1w[idx], B = B1w[idx];
    uint32_t s = (A & ~prev) | (B & prev);
    mask1[idx] = s;
    if (s) atomicOr(&chanAny[t * NB + b], s);
    prev = s;
  }
}

// --- conv2+pool: 10 t per block (250 lanes), 16 oc per thread -------------
__global__ __launch_bounds__(256, 2) void conv2_ab(const uint32_t* __restrict__ mask1,
                                                   const uint32_t* __restrict__ chanAny,
                                                   const double* __restrict__ W2R,
                                                   unsigned char* __restrict__ A2,
                                                   unsigned char* __restrict__ B2) {
  const int tc = blockIdx.x;   // 0..9 -> t0 = tc*10
  const int b  = blockIdx.y;   // 0..63
  const int og = blockIdx.z;   // 0..3 -> oc og*16..+15
  const int t0 = tc * 10;
  __shared__ uint32_t sM[10 * 196];
  const int tid = threadIdx.x;

  for (int e = tid; e < 490; e += 256) {
    int fr = e / 49, w4 = e % 49;
    ((uint4*)sM)[e] =
        *((const uint4*)(mask1 + (size_t)((t0 + fr) * NB + b) * 196) + w4);
  }
  __syncthreads();

  const int th = tid / 25, p = tid - th * 25;
  int thc = th > 9 ? 9 : th;
  uint32_t ca = chanAny[(t0 + thc) * NB + b];
  #pragma unroll
  for (int off = 32; off > 0; off >>= 1) ca |= __shfl_xor(ca, off);
  const uint32_t skipOr = ca;  // wave-uniform union over the wave's timesteps

  if (tid < 250) {
    const int oh = p / 5, ow = p - oh * 5;
    uint32_t m[36];
    const uint32_t* basep = &sM[th * 196 + (2 * oh) * 14 + 2 * ow];
    #pragma unroll
    for (int iy = 0; iy < 6; ++iy)
      #pragma unroll
      for (int ix = 0; ix < 6; ++ix) m[iy * 6 + ix] = basep[iy * 14 + ix];

    double a[16];
    #pragma unroll
    for (int i = 0; i < 16; ++i) a[i] = 0.0;
    const double* Wb = W2R + (size_t)og * 18432;  // 32*36*16
    for (int c = 0; c < 32; ++c) {
      if (!((skipOr >> c) & 1u)) continue;
      const double* wc = Wb + c * 576;
      #pragma unroll
      for (int pos = 0; pos < 36; ++pos) {
        double bd = (double)((m[pos] >> c) & 1u);
        const double* wp = wc + pos * 16;
        #pragma unroll
        for (int oj = 0; oj < 16; ++oj) a[oj] = fma(bd, wp[oj], a[oj]);
      }
    }
    unsigned ablo = 0, abhi = 0, bblo = 0, bbhi = 0;
    #pragma unroll
    for (int oj = 0; oj < 8; ++oj) {
      float cl = (float)(a[oj] * 0.25);
      float ch = (float)(a[8 + oj] * 0.25);
      if (cl > 1.0f) ablo |= 1u << oj;
      if (cl > 2.0f) bblo |= 1u << oj;
      if (ch > 1.0f) abhi |= 1u << oj;
      if (ch > 2.0f) bbhi |= 1u << oj;
    }
    const int t = t0 + th;
    size_t idx = ((size_t)(t * NB + b) * 25 + p) * 8 + og * 2;
    A2[idx] = (unsigned char)ablo; A2[idx + 1] = (unsigned char)abhi;
    B2[idx] = (unsigned char)bblo; B2[idx + 1] = (unsigned char)bbhi;
  }
}

// --- LIF2 scan: 64 oc per u64 word ----------------------------------------
__global__ __launch_bounds__(256) void scan2(const uint64_t* __restrict__ A2q,
                                             const uint64_t* __restrict__ B2q,
                                             uint64_t* __restrict__ mask2) {
  int chain = blockIdx.x * 256 + threadIdx.x;
  if (chain >= NB * 25) return;
  int b = chain / 25, p = chain % 25;
  uint64_t prev = 0;
  #pragma unroll 4
  for (int t = 0; t < NSTEPS; ++t) {
    size_t idx = (size_t)(t * NB + b) * 25 + p;
    uint64_t A = A2q[idx], B = B2q[idx];
    uint64_t s = (A & ~prev) | (B & prev);
    mask2[idx] = s;
    prev = s;
  }
}

// --- FC from packed masks: cur3[t,b,10] -----------------------------------
__global__ __launch_bounds__(256) void fc_kernel(const uint64_t* __restrict__ mask2,
                                                 const float* __restrict__ W2,
                                                 float* __restrict__ cur3) {
  int gid = blockIdx.x * 256 + threadIdx.x;
  if (gid >= NSTEPS * NB * 10) return;
  int tb = gid / 10, o = gid % 10;
  const uint64_t* m = mask2 + (size_t)tb * 25;
  const float* w = W2 + o * 1600;  // flat k = oc*25 + p
  double acc = 0.0;
  for (int p = 0; p < 25; ++p) {
    uint64_t mw = m[p];
    uint32_t lo = (uint32_t)mw, hi = (uint32_t)(mw >> 32);
    #pragma unroll 8
    for (int oc = 0; oc < 32; ++oc) {
      double bd = (double)((lo >> oc) & 1u);
      acc = fma(bd, (double)w[oc * 25 + p], acc);
    }
    #pragma unroll 8
    for (int oc = 32; oc < 64; ++oc) {
      double bd = (double)((hi >> (oc - 32)) & 1u);
      acc = fma(bd, (double)w[oc * 25 + p], acc);
    }
  }
  cur3[gid] = (float)acc;
}

// --- LIF3: out spikes [100,64,10] then mem [100,64,10] --------------------
__global__ __launch_bounds__(256) void lif3_kernel(const float* __restrict__ cur3,
                                                   float* __restrict__ out) {
  int bo = blockIdx.x * 256 + threadIdx.x;
  if (bo >= NB * 10) return;
  float prev = 0.0f;
  for (int t = 0; t < NSTEPS; ++t) {
    float cur = cur3[t * (NB * 10) + bo];
    float mem = cur - prev;
    bool s = mem > 1.0f;
    out[t * (NB * 10) + bo] = s ? 1.0f : 0.0f;
    out[NSTEPS * NB * 10 + t * (NB * 10) + bo] = mem;
    prev = s ? 1.0f : 0.0f;
  }
}

extern "C" void kernel_launch(void* const* d_in, const int* in_sizes, int n_in,
                              void* d_out, int out_size, void* d_ws, size_t ws_size,
                              hipStream_t stream) {
  const float* x    = (const float*)d_in[0];
  const float* W_in = (const float*)d_in[1];
  const float* W_h1 = (const float*)d_in[2];
  const float* W_h2 = (const float*)d_in[3];
  float* out = (float*)d_out;

  unsigned char* ws = (unsigned char*)d_ws;
  double*        W1R     = (double*)(ws + 0);          //     27,648
  double*        W2R     = (double*)(ws + 27648);      //    589,824
  unsigned char* spk0c   = ws + 617472;                //  6,553,600
  unsigned char* A1      = ws + 7171072;               //  5,017,600
  unsigned char* B1      = ws + 12188672;              //  5,017,600
  uint32_t*      mask1   = (uint32_t*)(ws + 17206272); //  5,017,600
  uint32_t*      chanAny = (uint32_t*)(ws + 22223872); //     25,600
  unsigned char* A2      = ws + 22249472;              //  1,280,000
  unsigned char* B2      = ws + 23529472;              //  1,280,000
  uint64_t*      mask2   = (uint64_t*)(ws + 24809472); //  1,280,000
  float*         cur3    = (float*)(ws + 26089472);    //    256,000

  weff_all<<<302, 256, 0, stream>>>(W_in, W_h1, W1R, W2R);
  gen_spikes<<<NSTEPS * NB * 4, 256, 0, stream>>>(x, spk0c);
  hipMemsetAsync(chanAny, 0, NSTEPS * NB * 4, stream);
  conv1_ab<<<dim3(1225, 4), 256, 0, stream>>>(spk0c, W1R, A1, B1);
  scan1<<<(NB * 196 + 255) / 256, 256, 0, stream>>>((const uint32_t*)A1,
                                                    (const uint32_t*)B1, mask1, chanAny);
  conv2_ab<<<dim3(10, NB, 4), 256, 0, stream>>>(mask1, chanAny, W2R, A2, B2);
  scan2<<<(NB * 25 + 255) / 256, 256, 0, stream>>>((const uint64_t*)A2,
                                                   (const uint64_t*)B2, mask2);
  fc_kernel<<<(NSTEPS * NB * 10 + 255) / 256, 256, 0, stream>>>(mask2, W_h2, cur3);
  lif3_kernel<<<3, 256, 0, stream>>>(cur3, out);
}

// Round 6
// 644.245 us; speedup vs baseline: 1.6825x; 1.6825x over previous
//
#include <hip/hip_runtime.h>
#include <stdint.h>

// ---------------------------------------------------------------------------
// Conv-SNN, 100 steps, B=64, BETA=0.
// Round 6: round 5 minus the scan1 atomicOr disaster.
//  - scan1/scan2: register batch-prefetch (25 steps), 64-thread blocks, no atomics
//  - chanAny buffer deleted; conv2 computes its wave's channel-skip union
//    directly from the LDS-staged mask1 tile (bit-identical results).
// f64 accumulation, summation order unchanged (absmax 0.0 lineage).
// ---------------------------------------------------------------------------

#define NSTEPS 100
#define NB 64

__device__ __forceinline__ uint32_t rotl32(uint32_t v, uint32_t r) {
  return (v << r) | (v >> (32u - r));
}

__device__ __forceinline__ void threefry2x32(uint32_t k0, uint32_t k1,
                                             uint32_t& x0, uint32_t& x1) {
  uint32_t k2 = k0 ^ k1 ^ 0x1BD11BDAu;
  x0 += k0; x1 += k1;
#define TF_R(r) { x0 += x1; x1 = rotl32(x1, r); x1 ^= x0; }
  TF_R(13u) TF_R(15u) TF_R(26u) TF_R(6u)
  x0 += k1; x1 += k2 + 1u;
  TF_R(17u) TF_R(29u) TF_R(16u) TF_R(24u)
  x0 += k2; x1 += k0 + 2u;
  TF_R(13u) TF_R(15u) TF_R(26u) TF_R(6u)
  x0 += k0; x1 += k1 + 3u;
  TF_R(17u) TF_R(29u) TF_R(16u) TF_R(24u)
  x0 += k1; x1 += k2 + 4u;
  TF_R(13u) TF_R(15u) TF_R(26u) TF_R(6u)
  x0 += k2; x1 += k0 + 5u;
#undef TF_R
}

__device__ __forceinline__ double fold_pool_w(const float* W, int base, int pos) {
  int iy = pos / 6, ix = pos % 6;
  double w = 0.0;
  for (int dy = 0; dy < 2; ++dy) {
    int ky = iy - dy; if (ky < 0 || ky > 4) continue;
    for (int dx = 0; dx < 2; ++dx) {
      int kx = ix - dx; if (kx < 0 || kx > 4) continue;
      w += (double)W[base + ky * 5 + kx];
    }
  }
  return w;
}

// Fused folded-pool weights.
// W1R: [og4][pos36][c3][oj8]   (oc = og*8+oj)
// W2R: [og4][c32][pos36][oj16] (oc = og*16+oj)
__global__ __launch_bounds__(256) void weff_all(const float* __restrict__ W_in,
                                                const float* __restrict__ W_h1,
                                                double* __restrict__ W1R,
                                                double* __restrict__ W2R) {
  int e = blockIdx.x * 256 + threadIdx.x;
  if (e < 3456) {
    int oj = e & 7, c = (e >> 3) % 3, pos = ((e >> 3) / 3) % 36, og = (e >> 3) / 108;
    int oc = og * 8 + oj;
    W1R[e] = fold_pool_w(W_in, (oc * 3 + c) * 25, pos);
  } else if (e < 3456 + 73728) {
    int e2 = e - 3456;
    int oj = e2 & 15, pos = (e2 >> 4) % 36, c = ((e2 >> 4) / 36) % 32, og = e2 / 18432;
    int oc = og * 16 + oj;
    W2R[e2] = fold_pool_w(W_h1, (oc * 32 + c) * 25, pos);
  }
}

// --- spike gen: per-pixel 3-bit channel codes [t,b,1024] bytes ------------
__global__ __launch_bounds__(256) void gen_spikes(const float* __restrict__ x,
                                                  unsigned char* __restrict__ spk0c) {
  int g = blockIdx.x * 256 + threadIdx.x;
  if (g >= NSTEPS * NB * 1024) return;
  int tb = g >> 10, pix = g & 1023;
  int b = tb & 63;
  unsigned code = 0;
  #pragma unroll
  for (int c = 0; c < 3; ++c) {
    uint32_t i = (uint32_t)((tb * 3 + c) * 1024 + pix);
    uint32_t x0 = 0u, x1 = i;
    threefry2x32(0u, 1u, x0, x1);
    uint32_t bits = x0 ^ x1;
    float u = __uint_as_float((bits >> 9) | 0x3f800000u) - 1.0f;
    float xv = x[(b * 3 + c) * 1024 + pix];
    code |= (u < 2.0f * xv) ? (1u << c) : 0u;
  }
  spk0c[g] = (unsigned char)code;
}

// --- conv1+pool, 4 t per thread, flat over (tq,b,p), emits A/B bytes ------
// grid: (1225, 4og). Block spans at most 3 (tq,b) frames; all staged in LDS.
__global__ __launch_bounds__(256, 4) void conv1_ab(const unsigned char* __restrict__ spk0c,
                                                   const double* __restrict__ W1R,
                                                   unsigned char* __restrict__ A1,
                                                   unsigned char* __restrict__ B1) {
  const int og  = blockIdx.y;
  const int tid = threadIdx.x;
  const int id0 = blockIdx.x * 256;
  const int id  = id0 + tid;
  const int tb0 = id0 / 196;               // first (tq*64+b) in block
  __shared__ unsigned char sC[3][4][1024]; // [seg][tt][pix]

  #pragma unroll
  for (int k = 0; k < 3; ++k) {
    int idx = tid + k * 256;               // 0..767
    int fi = idx >> 6, lane = idx & 63;    // fi 0..11
    int seg = fi >> 2, tt = fi & 3;        // seg 0..2
    int tb = tb0 + seg; if (tb > 1599) tb = 1599;
    int b = tb & 63, tq = tb >> 6;
    ((uint4*)sC)[idx] =
        ((const uint4*)(spk0c + (size_t)((tq * 4 + tt) * NB + b) * 1024))[lane];
  }
  __syncthreads();

  const int tb  = id / 196;
  const int p   = id - tb * 196;
  const int seg = tb - tb0;                // 0..2
  const int b = tb & 63, tq = tb >> 6;
  const int oh = p / 14, ow = p - oh * 14;
  const unsigned char* base = &sC[seg][0][(2 * oh) * 32 + 2 * ow];
  const double* Wb = W1R + og * 864;

  double a[32];
  #pragma unroll
  for (int i = 0; i < 32; ++i) a[i] = 0.0;

  #pragma unroll
  for (int iy = 0; iy < 6; ++iy) {
    #pragma unroll
    for (int ix = 0; ix < 6; ++ix) {
      const int pos = iy * 6 + ix, off = iy * 32 + ix;
      unsigned c0 = base[0 * 1024 + off];
      unsigned c1 = base[1 * 1024 + off];
      unsigned c2 = base[2 * 1024 + off];
      unsigned c3 = base[3 * 1024 + off];
      #pragma unroll
      for (int c = 0; c < 3; ++c) {
        double b0 = (double)((c0 >> c) & 1u);
        double b1 = (double)((c1 >> c) & 1u);
        double b2 = (double)((c2 >> c) & 1u);
        double b3 = (double)((c3 >> c) & 1u);
        const double* wp = Wb + pos * 24 + c * 8;
        #pragma unroll
        for (int oj = 0; oj < 8; ++oj) {
          double w = wp[oj];
          a[0 * 8 + oj] = fma(b0, w, a[0 * 8 + oj]);
          a[1 * 8 + oj] = fma(b1, w, a[1 * 8 + oj]);
          a[2 * 8 + oj] = fma(b2, w, a[2 * 8 + oj]);
          a[3 * 8 + oj] = fma(b3, w, a[3 * 8 + oj]);
        }
      }
    }
  }

  #pragma unroll
  for (int tt = 0; tt < 4; ++tt) {
    unsigned ab = 0, bb = 0;
    #pragma unroll
    for (int oj = 0; oj < 8; ++oj) {
      float cur = (float)(a[tt * 8 + oj] * 0.25);
      if (cur > 1.0f) ab |= 1u << oj;
      if (cur > 2.0f) bb |= 1u << oj;
    }
    int t = tq * 4 + tt;
    size_t idx = ((size_t)(t * NB + b) * 196 + p) * 4 + og;
    A1[idx] = (unsigned char)ab;
    B1[idx] = (unsigned char)bb;
  }
}

// --- LIF1 scan: batched register prefetch, no atomics ---------------------
__global__ __launch_bounds__(64) void scan1(const uint32_t* __restrict__ A1w,
                                            const uint32_t* __restrict__ B1w,
                                            uint32_t* __restrict__ mask1) {
  int chain = blockIdx.x * 64 + threadIdx.x;
  if (chain >= NB * 196) return;
  int b = chain / 196, p = chain % 196;
  const size_t stride = (size_t)NB * 196;
  size_t base = (size_t)b * 196 + p;
  uint32_t prev = 0;
  #pragma unroll
  for (int seg = 0; seg < 4; ++seg) {
    uint32_t Abuf[25], Bbuf[25];
    size_t sb = base + (size_t)(seg * 25) * stride;
    #pragma unroll
    for (int i = 0; i < 25; ++i) {
      Abuf[i] = A1w[sb + i * stride];
      Bbuf[i] = B1w[sb + i * stride];
    }
    #pragma unroll
    for (int i = 0; i < 25; ++i) {
      uint32_t s = (Abuf[i] & ~prev) | (Bbuf[i] & prev);
      mask1[sb + i * stride] = s;
      prev = s;
    }
  }
}

// --- conv2+pool: 10 t per block (250 lanes), 16 oc, skip from LDS tile ----
__global__ __launch_bounds__(256, 2) void conv2_ab(const uint32_t* __restrict__ mask1,
                                                   const double* __restrict__ W2R,
                                                   unsigned char* __restrict__ A2,
                                                   unsigned char* __restrict__ B2) {
  const int tc = blockIdx.x;   // 0..9 -> t0 = tc*10
  const int b  = blockIdx.y;   // 0..63
  const int og = blockIdx.z;   // 0..3 -> oc og*16..+15
  const int t0 = tc * 10;
  __shared__ uint32_t sM[10 * 196];
  const int tid = threadIdx.x;

  for (int e = tid; e < 490; e += 256) {
    int fr = e / 49, w4 = e % 49;
    ((uint4*)sM)[e] =
        *((const uint4*)(mask1 + (size_t)((t0 + fr) * NB + b) * 196) + w4);
  }
  __syncthreads();

  // wave channel-skip union over the wave's covered timesteps (from LDS)
  const int lane = tid & 63;
  int thLo = (tid & ~63) / 25;
  int thHi = ((tid & ~63) + 63) / 25; if (thHi > 9) thHi = 9;
  uint32_t ca = 0;
  for (int e = thLo * 196 + lane; e < (thHi + 1) * 196; e += 64) ca |= sM[e];
  #pragma unroll
  for (int off = 32; off > 0; off >>= 1) ca |= __shfl_xor(ca, off);
  const uint32_t skipOr = ca;

  const int th = tid / 25, p = tid - th * 25;
  if (tid < 250) {
    const int oh = p / 5, ow = p - oh * 5;
    uint32_t m[36];
    const uint32_t* basep = &sM[th * 196 + (2 * oh) * 14 + 2 * ow];
    #pragma unroll
    for (int iy = 0; iy < 6; ++iy)
      #pragma unroll
      for (int ix = 0; ix < 6; ++ix) m[iy * 6 + ix] = basep[iy * 14 + ix];

    double a[16];
    #pragma unroll
    for (int i = 0; i < 16; ++i) a[i] = 0.0;
    const double* Wb = W2R + (size_t)og * 18432;  // 32*36*16
    for (int c = 0; c < 32; ++c) {
      if (!((skipOr >> c) & 1u)) continue;
      const double* wc = Wb + c * 576;
      #pragma unroll
      for (int pos = 0; pos < 36; ++pos) {
        double bd = (double)((m[pos] >> c) & 1u);
        const double* wp = wc + pos * 16;
        #pragma unroll
        for (int oj = 0; oj < 16; ++oj) a[oj] = fma(bd, wp[oj], a[oj]);
      }
    }
    unsigned ablo = 0, abhi = 0, bblo = 0, bbhi = 0;
    #pragma unroll
    for (int oj = 0; oj < 8; ++oj) {
      float cl = (float)(a[oj] * 0.25);
      float ch = (float)(a[8 + oj] * 0.25);
      if (cl > 1.0f) ablo |= 1u << oj;
      if (cl > 2.0f) bblo |= 1u << oj;
      if (ch > 1.0f) abhi |= 1u << oj;
      if (ch > 2.0f) bbhi |= 1u << oj;
    }
    const int t = t0 + th;
    size_t idx = ((size_t)(t * NB + b) * 25 + p) * 8 + og * 2;
    A2[idx] = (unsigned char)ablo; A2[idx + 1] = (unsigned char)abhi;
    B2[idx] = (unsigned char)bblo; B2[idx + 1] = (unsigned char)bbhi;
  }
}

// --- LIF2 scan: 64 oc per u64 word, batched prefetch ----------------------
__global__ __launch_bounds__(64) void scan2(const uint64_t* __restrict__ A2q,
                                            const uint64_t* __restrict__ B2q,
                                            uint64_t* __restrict__ mask2) {
  int chain = blockIdx.x * 64 + threadIdx.x;
  if (chain >= NB * 25) return;
  int b = chain / 25, p = chain % 25;
  const size_t stride = (size_t)NB * 25;
  size_t base = (size_t)b * 25 + p;
  uint64_t prev = 0;
  #pragma unroll
  for (int seg = 0; seg < 4; ++seg) {
    uint64_t Abuf[25], Bbuf[25];
    size_t sb = base + (size_t)(seg * 25) * stride;
    #pragma unroll
    for (int i = 0; i < 25; ++i) {
      Abuf[i] = A2q[sb + i * stride];
      Bbuf[i] = B2q[sb + i * stride];
    }
    #pragma unroll
    for (int i = 0; i < 25; ++i) {
      uint64_t s = (Abuf[i] & ~prev) | (Bbuf[i] & prev);
      mask2[sb + i * stride] = s;
      prev = s;
    }
  }
}

// --- FC from packed masks: cur3[t,b,10] -----------------------------------
__global__ __launch_bounds__(256) void fc_kernel(const uint64_t* __restrict__ mask2,
                                                 const float* __restrict__ W2,
                                                 float* __restrict__ cur3) {
  int gid = blockIdx.x * 256 + threadIdx.x;
  if (gid >= NSTEPS * NB * 10) return;
  int tb = gid / 10, o = gid % 10;
  const uint64_t* m = mask2 + (size_t)tb * 25;
  const float* w = W2 + o * 1600;  // flat k = oc*25 + p
  double acc = 0.0;
  for (int p = 0; p < 25; ++p) {
    uint64_t mw = m[p];
    uint32_t lo = (uint32_t)mw, hi = (uint32_t)(mw >> 32);
    #pragma unroll 8
    for (int oc = 0; oc < 32; ++oc) {
      double bd = (double)((lo >> oc) & 1u);
      acc = fma(bd, (double)w[oc * 25 + p], acc);
    }
    #pragma unroll 8
    for (int oc = 32; oc < 64; ++oc) {
      double bd = (double)((hi >> (oc - 32)) & 1u);
      acc = fma(bd, (double)w[oc * 25 + p], acc);
    }
  }
  cur3[gid] = (float)acc;
}

// --- LIF3: out spikes [100,64,10] then mem [100,64,10] --------------------
__global__ __launch_bounds__(256) void lif3_kernel(const float* __restrict__ cur3,
                                                   float* __restrict__ out) {
  int bo = blockIdx.x * 256 + threadIdx.x;
  if (bo >= NB * 10) return;
  float prev = 0.0f;
  for (int t = 0; t < NSTEPS; ++t) {
    float cur = cur3[t * (NB * 10) + bo];
    float mem = cur - prev;
    bool s = mem > 1.0f;
    out[t * (NB * 10) + bo] = s ? 1.0f : 0.0f;
    out[NSTEPS * NB * 10 + t * (NB * 10) + bo] = mem;
    prev = s ? 1.0f : 0.0f;
  }
}

extern "C" void kernel_launch(void* const* d_in, const int* in_sizes, int n_in,
                              void* d_out, int out_size, void* d_ws, size_t ws_size,
                              hipStream_t stream) {
  const float* x    = (const float*)d_in[0];
  const float* W_in = (const float*)d_in[1];
  const float* W_h1 = (const float*)d_in[2];
  const float* W_h2 = (const float*)d_in[3];
  float* out = (float*)d_out;

  unsigned char* ws = (unsigned char*)d_ws;
  double*        W1R     = (double*)(ws + 0);          //     27,648
  double*        W2R     = (double*)(ws + 27648);      //    589,824
  unsigned char* spk0c   = ws + 617472;                //  6,553,600
  unsigned char* A1      = ws + 7171072;               //  5,017,600
  unsigned char* B1      = ws + 12188672;              //  5,017,600
  uint32_t*      mask1   = (uint32_t*)(ws + 17206272); //  5,017,600
  unsigned char* A2      = ws + 22249472;              //  1,280,000
  unsigned char* B2      = ws + 23529472;              //  1,280,000
  uint64_t*      mask2   = (uint64_t*)(ws + 24809472); //  1,280,000
  float*         cur3    = (float*)(ws + 26089472);    //    256,000

  weff_all<<<302, 256, 0, stream>>>(W_in, W_h1, W1R, W2R);
  gen_spikes<<<NSTEPS * NB * 4, 256, 0, stream>>>(x, spk0c);
  conv1_ab<<<dim3(1225, 4), 256, 0, stream>>>(spk0c, W1R, A1, B1);
  scan1<<<(NB * 196 + 63) / 64, 64, 0, stream>>>((const uint32_t*)A1,
                                                 (const uint32_t*)B1, mask1);
  conv2_ab<<<dim3(10, NB, 4), 256, 0, stream>>>(mask1, W2R, A2, B2);
  scan2<<<(NB * 25 + 63) / 64, 64, 0, stream>>>((const uint64_t*)A2,
                                                (const uint64_t*)B2, mask2);
  fc_kernel<<<(NSTEPS * NB * 10 + 255) / 256, 256, 0, stream>>>(mask2, W_h2, cur3);
  lif3_kernel<<<3, 256, 0, stream>>>(cur3, out);
}